// Round 1
// baseline (9380.892 us; speedup 1.0000x reference)
//
#include <hip/hip_runtime.h>
#include <hip/hip_bf16.h>

#define LAYERS 12
#define NHEAD  12
#define DMODEL 768
#define HDIM   64
#define VOCAB  50257
#define VPAD   50304
#define NB     4
#define SEQ    1024
#define ROWS   (NB * SEQ)      // 4096
#define LN_EPS 1e-5f

typedef __attribute__((ext_vector_type(8))) short  short8;   // 8 x bf16 (4 VGPRs)
typedef __attribute__((ext_vector_type(4))) float  floatx4;
typedef __attribute__((ext_vector_type(4))) unsigned int uintx4;
using bf16 = __hip_bfloat16;

// ---------------------------------------------------------------- embedding
__global__ void embed_kernel(const int* __restrict__ idx, const float* __restrict__ wte,
                             const float* __restrict__ wpe, float* __restrict__ x) {
    int row = blockIdx.x;                 // 0..4095
    int s   = row & (SEQ - 1);
    int tok = idx[row];
    const float* we = wte + (size_t)tok * DMODEL;
    const float* pe = wpe + (size_t)s * DMODEL;
    float* xo = x + (size_t)row * DMODEL;
    for (int d = threadIdx.x; d < DMODEL; d += blockDim.x) xo[d] = we[d] + pe[d];
}

// ---------------------------------------------------------------- layernorm (fp32 in -> bf16 out)
__global__ void ln_kernel(const float* __restrict__ x, const float* __restrict__ w,
                          const float* __restrict__ b, bf16* __restrict__ out) {
    int row = blockIdx.x;
    int t = threadIdx.x;
    const float* xr = x + (size_t)row * DMODEL;
    float v0 = xr[t], v1 = xr[t + 256], v2 = xr[t + 512];

    __shared__ float red[8];
    // mean
    float s = v0 + v1 + v2;
    for (int off = 32; off; off >>= 1) s += __shfl_xor(s, off);
    int lane = t & 63, wv = t >> 6;
    if (lane == 0) red[wv] = s;
    __syncthreads();
    float mu = (red[0] + red[1] + red[2] + red[3]) * (1.0f / DMODEL);
    // var
    float d0 = v0 - mu, d1 = v1 - mu, d2 = v2 - mu;
    float q = d0 * d0 + d1 * d1 + d2 * d2;
    for (int off = 32; off; off >>= 1) q += __shfl_xor(q, off);
    if (lane == 0) red[4 + wv] = q;
    __syncthreads();
    float var = (red[4] + red[5] + red[6] + red[7]) * (1.0f / DMODEL);
    float rs = rsqrtf(var + LN_EPS);

    bf16* o = out + (size_t)row * DMODEL;
    o[t]       = __float2bfloat16(d0 * rs * w[t]       + b[t]);
    o[t + 256] = __float2bfloat16(d1 * rs * w[t + 256] + b[t + 256]);
    o[t + 512] = __float2bfloat16(d2 * rs * w[t + 512] + b[t + 512]);
}

// ---------------------------------------------------------------- transpose + fp32->bf16 cast
// in: fp32 [K][N] row-major; out: bf16 [Npad][K], out[n][k] = (n<N)? in[k][n] : 0
__global__ void transpose_cast(const float* __restrict__ in, bf16* __restrict__ out,
                               int K, int N, int Npad) {
    __shared__ float tile[32][33];
    int n0 = blockIdx.x * 32;
    int k0 = blockIdx.y * 32;
    int c  = threadIdx.x & 31;
    int r0 = threadIdx.x >> 5;   // 0..7
#pragma unroll
    for (int i = 0; i < 4; ++i) {
        int r = r0 + i * 8;
        int n = n0 + c;
        float v = 0.0f;
        if (n < N) v = in[(size_t)(k0 + r) * N + n];
        tile[r][c] = v;
    }
    __syncthreads();
#pragma unroll
    for (int i = 0; i < 4; ++i) {
        int r = r0 + i * 8;          // n-offset within tile
        out[(size_t)(n0 + r) * K + (k0 + c)] = __float2bfloat16(tile[c][r]);
    }
}

// ---------------------------------------------------------------- GEMM: C[M][N] = A[M][K] @ Bt[N][K]^T (+epilogue)
#define BM 128
#define BN 128
#define BK 64

enum { EPI_PLAIN = 0, EPI_BIAS = 1, EPI_BIAS_RES = 2, EPI_BIAS_GELU = 3 };

__device__ inline void store_val(float* p, float v) { *p = v; }
__device__ inline void store_val(bf16*  p, float v) { *p = __float2bfloat16(v); }

template <int EPI, bool GUARD_N, typename OUT_T>
__global__ __launch_bounds__(256) void gemm_kernel(
    const bf16* __restrict__ A,    // [M][K] bf16
    const bf16* __restrict__ Bt,   // [Npad][K] bf16 (W^T)
    const float* __restrict__ bias,// [N] or null
    const float* __restrict__ R,   // residual [M][N] or null
    OUT_T* __restrict__ C,         // [M][N]
    int N, int K)
{
    __shared__ __align__(16) unsigned short As[BM * BK];
    __shared__ __align__(16) unsigned short Bs[BN * BK];

    const int tid = threadIdx.x;
    const int m0 = blockIdx.y * BM;
    const int n0 = blockIdx.x * BN;
    const int nk = K / BK;

    const bf16* Ab = A  + (size_t)m0 * K;
    const bf16* Bb = Bt + (size_t)n0 * K;

    uintx4 pa[4], pb[4];

    auto LOAD = [&](int t) {
        const int k0 = t * BK;
#pragma unroll
        for (int c = 0; c < 4; ++c) {
            int id = c * 256 + tid;
            int row = id >> 3, sl = id & 7;
            pa[c] = *(const uintx4*)(Ab + (size_t)row * K + k0 + sl * 8);
            pb[c] = *(const uintx4*)(Bb + (size_t)row * K + k0 + sl * 8);
        }
    };
    auto STORE = [&]() {
#pragma unroll
        for (int c = 0; c < 4; ++c) {
            int id = c * 256 + tid;
            int row = id >> 3, sl = id & 7;
            int slw = sl ^ (row & 7);
            *(uintx4*)&As[row * BK + slw * 8] = pa[c];
            *(uintx4*)&Bs[row * BK + slw * 8] = pb[c];
        }
    };

    const int lane = tid & 63;
    const int wv = tid >> 6;
    const int wr = (wv >> 1) * 64, wc = (wv & 1) * 64;
    const int fr = lane & 15, kg = lane >> 4;

    floatx4 acc[4][4] = {};

    LOAD(0);
    for (int t = 0; t < nk; ++t) {
        __syncthreads();
        STORE();
        __syncthreads();
        if (t + 1 < nk) LOAD(t + 1);
#pragma unroll
        for (int kk = 0; kk < 2; ++kk) {
            short8 af[4], bfm[4];
#pragma unroll
            for (int m = 0; m < 4; ++m) {
                int row = wr + m * 16 + fr;
                int sl = (kk * 4 + kg) ^ (row & 7);
                af[m] = *(const short8*)&As[row * BK + sl * 8];
            }
#pragma unroll
            for (int n = 0; n < 4; ++n) {
                int row = wc + n * 16 + fr;
                int sl = (kk * 4 + kg) ^ (row & 7);
                bfm[n] = *(const short8*)&Bs[row * BK + sl * 8];
            }
#pragma unroll
            for (int m = 0; m < 4; ++m)
#pragma unroll
                for (int n = 0; n < 4; ++n)
                    acc[m][n] = __builtin_amdgcn_mfma_f32_16x16x32_bf16(af[m], bfm[n], acc[m][n], 0, 0, 0);
        }
    }

    // epilogue: D[row][col], row = (lane>>4)*4 + r, col = lane&15 (verified m89 layout)
#pragma unroll
    for (int m = 0; m < 4; ++m) {
#pragma unroll
        for (int n = 0; n < 4; ++n) {
            int col = n0 + wc + n * 16 + fr;
            if (GUARD_N && col >= N) continue;
            float bv = (EPI != EPI_PLAIN) ? bias[col] : 0.0f;
#pragma unroll
            for (int r = 0; r < 4; ++r) {
                int row = m0 + wr + m * 16 + kg * 4 + r;
                float v = acc[m][n][r] + bv;
                if (EPI == EPI_BIAS_RES) v += R[(size_t)row * N + col];
                if (EPI == EPI_BIAS_GELU) v = 0.5f * v * (1.0f + erff(v * 0.70710678f));
                store_val(&C[(size_t)row * N + col], v);
            }
        }
    }
}

// ---------------------------------------------------------------- attention (fp32, flash-style, 1 wave = 1 query row)
__global__ __launch_bounds__(256) void attn_kernel(const float* __restrict__ qkv,
                                                   bf16* __restrict__ out) {
    int bh = blockIdx.x;                 // 0..47
    int b = bh / NHEAD, h = bh % NHEAD;
    int q0 = blockIdx.y * 4;
    int tid = threadIdx.x, lane = tid & 63, wv = tid >> 6;
    int q = q0 + wv;

    __shared__ float Ks[64][65];
    __shared__ float Vs[64][65];
    __shared__ float Qs[4][65];
    __shared__ float Ps[4][64];

    const float* base = qkv + (size_t)b * SEQ * (3 * DMODEL) + h * HDIM;

    {   // stage the 4 Q rows (wave wv writes & later reads row wv — same-wave)
        int r = tid >> 6, d = tid & 63;
        Qs[r][d] = base[(size_t)(q0 + r) * (3 * DMODEL) + d];
    }

    float o_acc = 0.0f, m_run = -1e30f, l_run = 0.0f;
    int ntile_max = (q0 + 3) / 64 + 1;
    int ntile_me  = q / 64 + 1;

    for (int kt = 0; kt < ntile_max; ++kt) {
        __syncthreads();
        // stage K/V tile: 64 keys x 64 dims
#pragma unroll
        for (int c = 0; c < 4; ++c) {
            int id = c * 256 + tid;                  // 0..1023
            int rr = id >> 4, comp = (id & 15) * 4;
            const float* kro = base + (size_t)(kt * 64 + rr) * (3 * DMODEL) + DMODEL + comp;
            float4 kv = *(const float4*)kro;
            float4 vv = *(const float4*)(kro + DMODEL);
            Ks[rr][comp + 0] = kv.x; Ks[rr][comp + 1] = kv.y;
            Ks[rr][comp + 2] = kv.z; Ks[rr][comp + 3] = kv.w;
            Vs[rr][comp + 0] = vv.x; Vs[rr][comp + 1] = vv.y;
            Vs[rr][comp + 2] = vv.z; Vs[rr][comp + 3] = vv.w;
        }
        __syncthreads();

        if (kt < ntile_me) {
            int jg = kt * 64 + lane;
            float sc = -1e30f;
            if (jg <= q) {
                float a = 0.0f;
#pragma unroll 16
                for (int d = 0; d < HDIM; ++d) a += Ks[lane][d] * Qs[wv][d];
                sc = a * 0.125f;
            }
            float tm = sc;
            for (int off = 32; off; off >>= 1) tm = fmaxf(tm, __shfl_xor(tm, off));
            float mn = fmaxf(m_run, tm);
            float p = __expf(sc - mn);
            float ps = p;
            for (int off = 32; off; off >>= 1) ps += __shfl_xor(ps, off);
            float corr = __expf(m_run - mn);
            l_run = l_run * corr + ps;
            o_acc *= corr;
            m_run = mn;
            Ps[wv][lane] = p;
            asm volatile("s_waitcnt lgkmcnt(0)" ::: "memory");  // same-wave LDS RAW fence
            float oa = o_acc;
#pragma unroll 16
            for (int j = 0; j < 64; ++j) oa += Ps[wv][j] * Vs[j][lane];
            o_acc = oa;
        }
    }
    out[((size_t)b * SEQ + q) * DMODEL + h * HDIM + lane] = __float2bfloat16(o_acc / l_run);
}

// ---------------------------------------------------------------- cross-entropy
__global__ void loss_row_kernel(const float* __restrict__ logits, const int* __restrict__ labels,
                                float* __restrict__ partial) {
    int row = blockIdx.x;
    const float* lr = logits + (size_t)row * VOCAB;
    float m = -1e30f, l = 0.0f;
    for (int i = threadIdx.x; i < VOCAB; i += 256) {
        float v = lr[i];
        float nm = fmaxf(m, v);
        l = l * __expf(m - nm) + __expf(v - nm);
        m = nm;
    }
    for (int off = 32; off; off >>= 1) {
        float om = __shfl_xor(m, off), ol = __shfl_xor(l, off);
        float nm = fmaxf(m, om);
        l = l * __expf(m - nm) + ol * __expf(om - nm);
        m = nm;
    }
    __shared__ float sm[4], sl[4];
    int lane = threadIdx.x & 63, wv = threadIdx.x >> 6;
    if (lane == 0) { sm[wv] = m; sl[wv] = l; }
    __syncthreads();
    if (threadIdx.x == 0) {
        float M = sm[0], L = sl[0];
        for (int i = 1; i < 4; ++i) {
            float nm = fmaxf(M, sm[i]);
            L = L * __expf(M - nm) + sl[i] * __expf(sm[i] - nm);
            M = nm;
        }
        int lbl = labels[row];
        partial[row] = -(lr[lbl] - M - logf(L));
    }
}

__global__ void loss_final_kernel(const float* __restrict__ partial, float* __restrict__ out) {
    float s = 0.0f;
    for (int i = threadIdx.x; i < ROWS; i += 256) s += partial[i];
    for (int off = 32; off; off >>= 1) s += __shfl_xor(s, off);
    __shared__ float sb[4];
    int lane = threadIdx.x & 63, wv = threadIdx.x >> 6;
    if (lane == 0) sb[wv] = s;
    __syncthreads();
    if (threadIdx.x == 0) out[0] = (sb[0] + sb[1] + sb[2] + sb[3]) * (1.0f / ROWS);
}

// ---------------------------------------------------------------- launch
extern "C" void kernel_launch(void* const* d_in, const int* in_sizes, int n_in,
                              void* d_out, int out_size, void* d_ws, size_t ws_size,
                              hipStream_t stream) {
    const int*   idx   = (const int*)d_in[0];
    const int*   preds = (const int*)d_in[1];
    const float* wte   = (const float*)d_in[2];
    const float* wpe   = (const float*)d_in[3];
    const float* ln1w  = (const float*)d_in[4];
    const float* ln1b  = (const float*)d_in[5];
    const float* qkvw  = (const float*)d_in[6];
    const float* qkvb  = (const float*)d_in[7];
    const float* projw = (const float*)d_in[8];
    const float* projb = (const float*)d_in[9];
    const float* ln2w  = (const float*)d_in[10];
    const float* ln2b  = (const float*)d_in[11];
    const float* f1w   = (const float*)d_in[12];
    const float* f1b   = (const float*)d_in[13];
    const float* f2w   = (const float*)d_in[14];
    const float* f2b   = (const float*)d_in[15];
    const float* lnfw  = (const float*)d_in[16];
    const float* lnfb  = (const float*)d_in[17];
    const float* lmw   = (const float*)d_in[18];

    char* ws = (char*)d_ws;
    size_t off = 0;
    auto alloc = [&](size_t bytes) { void* p = ws + off; off = (off + bytes + 255) & ~255ULL; return p; };

    bf16*  wT      = (bf16*) alloc((size_t)VPAD * DMODEL * sizeof(bf16));   // 77.3 MB
    float* x       = (float*)alloc((size_t)ROWS * DMODEL * 4);              // 12.6 MB
    bf16*  hbuf    = (bf16*) alloc((size_t)ROWS * DMODEL * 2);              //  6.3 MB
    float* qkvbuf  = (float*)alloc((size_t)ROWS * 3 * DMODEL * 4);          // 37.7 MB
    bf16*  obuf    = (bf16*) alloc((size_t)ROWS * DMODEL * 2);              //  6.3 MB
    bf16*  midbuf  = (bf16*) alloc((size_t)ROWS * 4 * DMODEL * 2);          // 25.2 MB
    float* partial = (float*)alloc((size_t)ROWS * 4);

    embed_kernel<<<ROWS, 256, 0, stream>>>(idx, wte, wpe, x);

    for (int l = 0; l < LAYERS; ++l) {
        ln_kernel<<<ROWS, 256, 0, stream>>>(x, ln1w + l * DMODEL, ln1b + l * DMODEL, hbuf);

        transpose_cast<<<dim3(3 * DMODEL / 32, DMODEL / 32), 256, 0, stream>>>(
            qkvw + (size_t)l * DMODEL * 3 * DMODEL, wT, DMODEL, 3 * DMODEL, 3 * DMODEL);
        gemm_kernel<EPI_BIAS, false, float><<<dim3(3 * DMODEL / BN, ROWS / BM), 256, 0, stream>>>(
            hbuf, wT, qkvb + l * 3 * DMODEL, nullptr, qkvbuf, 3 * DMODEL, DMODEL);

        attn_kernel<<<dim3(NB * NHEAD, SEQ / 4), 256, 0, stream>>>(qkvbuf, obuf);

        transpose_cast<<<dim3(DMODEL / 32, DMODEL / 32), 256, 0, stream>>>(
            projw + (size_t)l * DMODEL * DMODEL, wT, DMODEL, DMODEL, DMODEL);
        gemm_kernel<EPI_BIAS_RES, false, float><<<dim3(DMODEL / BN, ROWS / BM), 256, 0, stream>>>(
            obuf, wT, projb + l * DMODEL, x, x, DMODEL, DMODEL);

        ln_kernel<<<ROWS, 256, 0, stream>>>(x, ln2w + l * DMODEL, ln2b + l * DMODEL, hbuf);

        transpose_cast<<<dim3(4 * DMODEL / 32, DMODEL / 32), 256, 0, stream>>>(
            f1w + (size_t)l * DMODEL * 4 * DMODEL, wT, DMODEL, 4 * DMODEL, 4 * DMODEL);
        gemm_kernel<EPI_BIAS_GELU, false, bf16><<<dim3(4 * DMODEL / BN, ROWS / BM), 256, 0, stream>>>(
            hbuf, wT, f1b + l * 4 * DMODEL, nullptr, midbuf, 4 * DMODEL, DMODEL);

        transpose_cast<<<dim3(DMODEL / 32, 4 * DMODEL / 32), 256, 0, stream>>>(
            f2w + (size_t)l * 4 * DMODEL * DMODEL, wT, 4 * DMODEL, DMODEL, DMODEL);
        gemm_kernel<EPI_BIAS_RES, false, float><<<dim3(DMODEL / BN, ROWS / BM), 256, 0, stream>>>(
            midbuf, wT, f2b + l * DMODEL, x, x, DMODEL, 4 * DMODEL);
    }

    ln_kernel<<<ROWS, 256, 0, stream>>>(x, lnfw, lnfb, hbuf);

    transpose_cast<<<dim3(VPAD / 32, DMODEL / 32), 256, 0, stream>>>(lmw, wT, DMODEL, VOCAB, VPAD);
    float* logits = (float*)d_out;
    gemm_kernel<EPI_PLAIN, true, float><<<dim3(VPAD / BN, ROWS / BM), 256, 0, stream>>>(
        hbuf, wT, nullptr, nullptr, logits, VOCAB, DMODEL);

    loss_row_kernel<<<ROWS, 256, 0, stream>>>(logits, preds, partial);
    loss_final_kernel<<<1, 256, 0, stream>>>(partial, logits + (size_t)ROWS * VOCAB);
}